// Round 12
// baseline (183.578 us; speedup 1.0000x reference)
//
#include <hip/hip_runtime.h>
#include <math.h>

#define BATCH 4
#define CH    96
#define HH    48
#define WW    48
#define HWPIX (HH*WW)         // 2304
#define NPIX  (BATCH*HWPIX)   // 9216
#define WIN   13
#define WIN2  169
#define HALF  6
#define TOPK  8
#define NEGV  (-1000000000.0f)

// ---------------------------------------------------------------------------
// K1: transpose x (B,C,HW) -> xt (B*HW, C) [xt lives in d_out], + invn
// ---------------------------------------------------------------------------
__global__ __launch_bounds__(256) void k1_prep(
    const float* __restrict__ x, float* __restrict__ xt,
    float* __restrict__ invn)
{
    __shared__ float lds[96][33];
    int bid = blockIdx.x;          // 288 = 4 batches * 72 tiles
    int b   = bid / 72;
    int p0  = (bid % 72) * 32;
    int t   = threadIdx.x;

    #pragma unroll
    for (int it = 0; it < 12; ++it) {
        int e = t + it * 256;
        int c = e >> 5;
        int p = e & 31;
        lds[c][p] = x[(b * CH + c) * HWPIX + p0 + p];
    }
    __syncthreads();

    if (t < 32) {
        float ss = 0.f;
        #pragma unroll
        for (int c = 0; c < CH; ++c) { float v = lds[c][t]; ss += v * v; }
        invn[b * HWPIX + p0 + t] = 1.0f / fmaxf(sqrtf(ss), 1e-12f);
    }

    #pragma unroll
    for (int it = 0; it < 12; ++it) {
        int e = t + it * 256;
        int p = e / 96;
        int c = e - p * 96;
        xt[(b * HWPIX + p0 + p) * CH + c] = lds[c][p];
    }
}

// ---------------------------------------------------------------------------
// K2: two pixels per wave, interleaved latency chains. 1152 blocks x 256 thr.
//     No __syncthreads (own-rows are wave-private). Top-k chains for the two
//     pixels share one shuffle loop -> 2x latency overlap on the serial part.
// ---------------------------------------------------------------------------
__global__ __launch_bounds__(256) void k2_knn(
    const float* __restrict__ xt, const float* __restrict__ invn,
    const float* __restrict__ lnw, const float* __restrict__ lnb,
    float* __restrict__ enh)
{
    __shared__ float own[8][96];
    int t    = threadIdx.x;
    int wv   = t >> 6;
    int lane = t & 63;
    int gpA  = blockIdx.x * 8 + wv * 2;   // 1152 blocks * 8 px
    int gpB  = gpA + 1;

    int bA = gpA / HWPIX, pA = gpA - bA * HWPIX;
    int pyA = pA / WW,    pxA = pA - pyA * WW;
    int bB = gpB / HWPIX, pB = gpB - bB * HWPIX;
    int pyB = pB / WW,    pxB = pB - pyB * WW;

    // stage own rows (wave-private -> no barrier)
    own[wv*2  ][lane] = xt[gpA * CH + lane];
    own[wv*2+1][lane] = xt[gpB * CH + lane];
    if (lane < 32) {
        own[wv*2  ][lane + 64] = xt[gpA * CH + 64 + lane];
        own[wv*2+1][lane + 64] = xt[gpB * CH + 64 + lane];
    }
    float inpA = invn[gpA];
    float inpB = invn[gpB];

    // neighbor rows for 3 slots per pixel; slot2 aliases slot0 when n>=169
    int qA0, qA1, qA2, qB0, qB1, qB2;
    bool okA0, okA1, okA2, okB0, okB1, okB2;
    {
        int n, dy, dx, ny, nx, cy, cx;
        n = lane;       dy = n/WIN - HALF; dx = n - (dy+HALF)*WIN - HALF;
        ny = pyA+dy; nx = pxA+dx;
        okA0 = (ny>=0)&&(ny<HH)&&(nx>=0)&&(nx<WW);
        cy = min(max(ny,0),HH-1); cx = min(max(nx,0),WW-1);
        qA0 = bA*HWPIX + cy*WW + cx;
        ny = pyB+dy; nx = pxB+dx;
        okB0 = (ny>=0)&&(ny<HH)&&(nx>=0)&&(nx<WW);
        cy = min(max(ny,0),HH-1); cx = min(max(nx,0),WW-1);
        qB0 = bB*HWPIX + cy*WW + cx;

        n = lane+64;    dy = n/WIN - HALF; dx = n - (dy+HALF)*WIN - HALF;
        ny = pyA+dy; nx = pxA+dx;
        okA1 = (ny>=0)&&(ny<HH)&&(nx>=0)&&(nx<WW);
        cy = min(max(ny,0),HH-1); cx = min(max(nx,0),WW-1);
        qA1 = bA*HWPIX + cy*WW + cx;
        ny = pyB+dy; nx = pxB+dx;
        okB1 = (ny>=0)&&(ny<HH)&&(nx>=0)&&(nx<WW);
        cy = min(max(ny,0),HH-1); cx = min(max(nx,0),WW-1);
        qB1 = bB*HWPIX + cy*WW + cx;

        n = lane+128;   dy = n/WIN - HALF; dx = n - (dy+HALF)*WIN - HALF;
        bool in2 = (n < WIN2);
        ny = pyA+dy; nx = pxA+dx;
        okA2 = in2 && (ny>=0)&&(ny<HH)&&(nx>=0)&&(nx<WW);
        cy = min(max(ny,0),HH-1); cx = min(max(nx,0),WW-1);
        qA2 = in2 ? (bA*HWPIX + cy*WW + cx) : qA0;   // alias: no extra lines
        ny = pyB+dy; nx = pxB+dx;
        okB2 = in2 && (ny>=0)&&(ny<HH)&&(nx>=0)&&(nx<WW);
        cy = min(max(ny,0),HH-1); cx = min(max(nx,0),WW-1);
        qB2 = in2 ? (bB*HWPIX + cy*WW + cx) : qB0;
    }
    float inA0 = invn[qA0], inA1 = invn[qA1], inA2 = invn[qA2];
    float inB0 = invn[qB0], inB1 = invn[qB1], inB2 = invn[qB2];

    // interleaved dot products: 6 global float4 + 2 LDS b128 per iter,
    // 24 independent accumulators across the two pixels.
    const float4* ovA = (const float4*)(own[wv*2]);
    const float4* ovB = (const float4*)(own[wv*2+1]);
    const float4* pA0 = (const float4*)(xt + qA0 * CH);
    const float4* pA1 = (const float4*)(xt + qA1 * CH);
    const float4* pA2 = (const float4*)(xt + qA2 * CH);
    const float4* pB0 = (const float4*)(xt + qB0 * CH);
    const float4* pB1 = (const float4*)(xt + qB1 * CH);
    const float4* pB2 = (const float4*)(xt + qB2 * CH);
    float aA0=0.f,bA0_=0.f,cA0=0.f,dA0=0.f;
    float aA1=0.f,bA1_=0.f,cA1=0.f,dA1=0.f;
    float aA2=0.f,bA2_=0.f,cA2=0.f,dA2=0.f;
    float aB0=0.f,bB0_=0.f,cB0=0.f,dB0=0.f;
    float aB1=0.f,bB1_=0.f,cB1=0.f,dB1=0.f;
    float aB2=0.f,bB2_=0.f,cB2=0.f,dB2=0.f;
    #pragma unroll 2
    for (int s = 0; s < 24; ++s) {
        float4 oA = ovA[s];
        float4 oB = ovB[s];
        float4 nA0 = pA0[s], nA1 = pA1[s], nA2 = pA2[s];
        float4 nB0 = pB0[s], nB1 = pB1[s], nB2 = pB2[s];
        aA0 += oA.x*nA0.x; bA0_ += oA.y*nA0.y; cA0 += oA.z*nA0.z; dA0 += oA.w*nA0.w;
        aA1 += oA.x*nA1.x; bA1_ += oA.y*nA1.y; cA1 += oA.z*nA1.z; dA1 += oA.w*nA1.w;
        aA2 += oA.x*nA2.x; bA2_ += oA.y*nA2.y; cA2 += oA.z*nA2.z; dA2 += oA.w*nA2.w;
        aB0 += oB.x*nB0.x; bB0_ += oB.y*nB0.y; cB0 += oB.z*nB0.z; dB0 += oB.w*nB0.w;
        aB1 += oB.x*nB1.x; bB1_ += oB.y*nB1.y; cB1 += oB.z*nB1.z; dB1 += oB.w*nB1.w;
        aB2 += oB.x*nB2.x; bB2_ += oB.y*nB2.y; cB2 += oB.z*nB2.z; dB2 += oB.w*nB2.w;
    }
    float vA0 = okA0 ? ((aA0+bA0_)+(cA0+dA0)) * inpA * inA0 : NEGV;
    float vA1 = okA1 ? ((aA1+bA1_)+(cA1+dA1)) * inpA * inA1 : NEGV;
    float vA2 = okA2 ? ((aA2+bA2_)+(cA2+dA2)) * inpA * inA2 : NEGV;
    float vB0 = okB0 ? ((aB0+bB0_)+(cB0+dB0)) * inpB * inB0 : NEGV;
    float vB1 = okB1 ? ((aB1+bB1_)+(cB1+dB1)) * inpB * inB1 : NEGV;
    float vB2 = okB2 ? ((aB2+bB2_)+(cB2+dB2)) * inpB * inB2 : NEGV;

    // top-8 for BOTH pixels, chains interleaved in one loop
    float tvA[TOPK]; int tnA[TOPK];
    float tvB[TOPK]; int tnB[TOPK];
    #pragma unroll
    for (int r = 0; r < TOPK; ++r) {
        float va = vA0; int na = lane;
        if (vA1 > va) { va = vA1; na = lane + 64; }
        if (vA2 > va) { va = vA2; na = lane + 128; }
        float vb = vB0; int nb = lane;
        if (vB1 > vb) { vb = vB1; nb = lane + 64; }
        if (vB2 > vb) { vb = vB2; nb = lane + 128; }
        #pragma unroll
        for (int off = 1; off < 64; off <<= 1) {
            float ova = __shfl_xor(va, off);
            int   ona = __shfl_xor(na, off);
            float ovb = __shfl_xor(vb, off);
            int   onb = __shfl_xor(nb, off);
            if (ova > va || (ova == va && ona < na)) { va = ova; na = ona; }
            if (ovb > vb || (ovb == vb && onb < nb)) { vb = ovb; nb = onb; }
        }
        tvA[r] = va; tnA[r] = na;
        tvB[r] = vb; tnB[r] = nb;
        bool mineA = (na & 63) == lane; int ka = na >> 6;
        vA0 = (mineA && ka == 0) ? -2e9f : vA0;
        vA1 = (mineA && ka == 1) ? -2e9f : vA1;
        vA2 = (mineA && ka == 2) ? -2e9f : vA2;
        bool mineB = (nb & 63) == lane; int kb = nb >> 6;
        vB0 = (mineB && kb == 0) ? -2e9f : vB0;
        vB1 = (mineB && kb == 1) ? -2e9f : vB1;
        vB2 = (mineB && kb == 2) ? -2e9f : vB2;
    }

    // ---------------- finalize pixel A ----------------
    {
        float wts[TOPK]; int qn[TOPK];
        float wsum = 0.f;
        #pragma unroll
        for (int r = 0; r < TOPK; ++r) {
            float e = expf(tvA[r] - tvA[0]);
            wts[r] = e; wsum += e;
            int n  = tnA[r];
            int dy = n / WIN - HALF;
            int dx = n - (dy + HALF) * WIN - HALF;
            int gy = min(max(pyA + dy, 0), HH - 1);
            int gx = min(max(pxA + dx, 0), WW - 1);
            qn[r]  = bA * HWPIX + gy * WW + gx;
        }
        float winv = 1.0f / wsum;

        const float* xrow = xt + gpA * CH;
        float e1  = xrow[lane];
        float e2v = xrow[64 + (lane & 31)];
        float e2  = (lane < 32) ? e2v : 0.f;
        float s  = e1 + e2;
        float ss = e1 * e1 + e2 * e2;
        #pragma unroll
        for (int off = 1; off < 64; off <<= 1) {
            s  += __shfl_xor(s, off);
            ss += __shfl_xor(ss, off);
        }
        float mu  = s * (1.0f / 96.0f);
        float var = ss * (1.0f / 96.0f) - mu * mu;
        float rsd = rsqrtf(var + 1e-5f);

        float g1 = 0.f, g2 = 0.f;
        #pragma unroll
        for (int r = 0; r < TOPK; ++r) {
            const float* qrow = xt + qn[r] * CH;
            g1 += wts[r] * qrow[lane];
            g2 += wts[r] * qrow[64 + (lane & 31)];
        }
        g1 *= winv; g2 *= winv;

        enh[gpA * CH + lane] = g1 + (e1 - mu) * rsd * lnw[lane] + lnb[lane];
        if (lane < 32) {
            int c = 64 + lane;
            enh[gpA * CH + c] = g2 + (e2 - mu) * rsd * lnw[c] + lnb[c];
        }
    }
    // ---------------- finalize pixel B ----------------
    {
        float wts[TOPK]; int qn[TOPK];
        float wsum = 0.f;
        #pragma unroll
        for (int r = 0; r < TOPK; ++r) {
            float e = expf(tvB[r] - tvB[0]);
            wts[r] = e; wsum += e;
            int n  = tnB[r];
            int dy = n / WIN - HALF;
            int dx = n - (dy + HALF) * WIN - HALF;
            int gy = min(max(pyB + dy, 0), HH - 1);
            int gx = min(max(pxB + dx, 0), WW - 1);
            qn[r]  = bB * HWPIX + gy * WW + gx;
        }
        float winv = 1.0f / wsum;

        const float* xrow = xt + gpB * CH;
        float e1  = xrow[lane];
        float e2v = xrow[64 + (lane & 31)];
        float e2  = (lane < 32) ? e2v : 0.f;
        float s  = e1 + e2;
        float ss = e1 * e1 + e2 * e2;
        #pragma unroll
        for (int off = 1; off < 64; off <<= 1) {
            s  += __shfl_xor(s, off);
            ss += __shfl_xor(ss, off);
        }
        float mu  = s * (1.0f / 96.0f);
        float var = ss * (1.0f / 96.0f) - mu * mu;
        float rsd = rsqrtf(var + 1e-5f);

        float g1 = 0.f, g2 = 0.f;
        #pragma unroll
        for (int r = 0; r < TOPK; ++r) {
            const float* qrow = xt + qn[r] * CH;
            g1 += wts[r] * qrow[lane];
            g2 += wts[r] * qrow[64 + (lane & 31)];
        }
        g1 *= winv; g2 *= winv;

        enh[gpB * CH + lane] = g1 + (e1 - mu) * rsd * lnw[lane] + lnb[lane];
        if (lane < 32) {
            int c = 64 + lane;
            enh[gpB * CH + c] = g2 + (e2 - mu) * rsd * lnw[c] + lnb[c];
        }
    }
}

// ---------------------------------------------------------------------------
// K3: fused FFN. 8 px per block, 1152 blocks, 256 threads.
// ---------------------------------------------------------------------------
__global__ __launch_bounds__(256) void k3_ffn(
    const float* __restrict__ enh, const float* __restrict__ w1,
    const float* __restrict__ b1, const float* __restrict__ w2,
    const float* __restrict__ b2, float* __restrict__ out)
{
    __shared__ float hl[8][200];    // 6.25 KB, rows 800 B (16B-aligned)
    int g    = blockIdx.x;          // 1152 = 4 batches * 288 tiles
    int b    = g / 288;
    int p0   = (g % 288) * 8;
    int t    = threadIdx.x;
    int wv   = t >> 6;
    int lane = t & 63;
    int pix  = lane & 7;
    int sub  = lane >> 3;           // 0..7
    int grp  = wv * 8 + sub;        // 0..31
    int gp   = b * HWPIX + p0 + pix;

    float4 ereg[24];
    const float4* ev = (const float4*)(enh + gp * CH);
    #pragma unroll
    for (int c4 = 0; c4 < 24; ++c4) ereg[c4] = ev[c4];

    // phase A: 6 hidden units per lane
    const float4* w1v = (const float4*)w1;
    #pragma unroll
    for (int jj = 0; jj < 6; ++jj) {
        int j = grp * 6 + jj;
        float ax = 0.f, ay = 0.f, az = 0.f, aw = 0.f;
        #pragma unroll
        for (int c4 = 0; c4 < 24; ++c4) {
            float4 w4 = w1v[j * 24 + c4];
            ax += ereg[c4].x * w4.x; ay += ereg[c4].y * w4.y;
            az += ereg[c4].z * w4.z; aw += ereg[c4].w * w4.w;
        }
        hl[pix][j] = fmaxf(((ax + ay) + (az + aw)) + b1[j], 0.f);
    }
    __syncthreads();

    // phase B: 3 output channels per lane
    const float4* w2v = (const float4*)w2;
    const float4* hv4 = (const float4*)(&hl[pix][0]);
    float a0 = 0.f, a1 = 0.f, a2 = 0.f;
    int c0 = grp * 3;
    #pragma unroll 6
    for (int j4 = 0; j4 < 48; ++j4) {
        float4 hv = hv4[j4];
        float4 q0 = w2v[(c0 + 0) * 48 + j4];
        float4 q1 = w2v[(c0 + 1) * 48 + j4];
        float4 q2 = w2v[(c0 + 2) * 48 + j4];
        a0 += hv.x*q0.x + hv.y*q0.y + hv.z*q0.z + hv.w*q0.w;
        a1 += hv.x*q1.x + hv.y*q1.y + hv.z*q1.z + hv.w*q1.w;
        a2 += hv.x*q2.x + hv.y*q2.y + hv.z*q2.z + hv.w*q2.w;
    }

    float accs[3] = {a0, a1, a2};
    #pragma unroll
    for (int cc = 0; cc < 3; ++cc) {
        int c = c0 + cc;
        out[(b * CH + c) * HWPIX + p0 + pix] =
            enh[gp * CH + c] + accs[cc] + b2[c];
    }
}

// ---------------------------------------------------------------------------
extern "C" void kernel_launch(void* const* d_in, const int* in_sizes, int n_in,
                              void* d_out, int out_size, void* d_ws, size_t ws_size,
                              hipStream_t stream)
{
    const float* x   = (const float*)d_in[0];
    const float* w1  = (const float*)d_in[1];
    const float* b1  = (const float*)d_in[2];
    const float* w2  = (const float*)d_in[3];
    const float* b2  = (const float*)d_in[4];
    const float* lnw = (const float*)d_in[5];
    const float* lnb = (const float*)d_in[6];
    float* out = (float*)d_out;

    // xt lives in d_out (exactly NPIX*CH floats): k1 writes it, k2 consumes it,
    // k3 then overwrites d_out with the final output (stream-ordered).
    float* xt = out;

    // workspace: enh + invn = 893,952 floats = 3.58 MB
    float* ws   = (float*)d_ws;
    float* enh  = ws;                        // NPIX*96
    float* invn = enh + NPIX * CH;           // NPIX

    hipLaunchKernelGGL(k1_prep, dim3(288), dim3(256), 0, stream,
                       x, xt, invn);
    hipLaunchKernelGGL(k2_knn, dim3(NPIX / 8), dim3(256), 0, stream,
                       xt, invn, lnw, lnb, enh);
    hipLaunchKernelGGL(k3_ffn, dim3(1152), dim3(256), 0, stream,
                       enh, w1, b1, w2, b2, out);
}

// Round 15
// 126.756 us; speedup vs baseline: 1.4483x; 1.4483x over previous
//
#include <hip/hip_runtime.h>
#include <math.h>

#define BATCH 4
#define CH    96
#define HH    48
#define WW    48
#define HWPIX (HH*WW)         // 2304
#define NPIX  (BATCH*HWPIX)   // 9216
#define WIN   13
#define WIN2  169
#define HALF  6
#define TOPK  8
#define NEGV  (-1000000000.0f)

// ---------------------------------------------------------------------------
// K1: transpose x (B,C,HW) -> xt (B*HW, C) [xt lives in d_out],
//     + per-pixel invn / mu / rstd (population var, eps 1e-5)
// ---------------------------------------------------------------------------
__global__ __launch_bounds__(256) void k1_prep(
    const float* __restrict__ x, float* __restrict__ xt,
    float* __restrict__ invn, float* __restrict__ muv, float* __restrict__ rsd)
{
    __shared__ float lds[96][33];
    int bid = blockIdx.x;          // 288 = 4 batches * 72 tiles
    int b   = bid / 72;
    int p0  = (bid % 72) * 32;
    int t   = threadIdx.x;

    #pragma unroll
    for (int it = 0; it < 12; ++it) {
        int e = t + it * 256;
        int c = e >> 5;
        int p = e & 31;
        lds[c][p] = x[(b * CH + c) * HWPIX + p0 + p];
    }
    __syncthreads();

    if (t < 32) {
        float s = 0.f, ss = 0.f;
        #pragma unroll
        for (int c = 0; c < CH; ++c) { float v = lds[c][t]; s += v; ss += v * v; }
        int gpix = b * HWPIX + p0 + t;
        invn[gpix] = 1.0f / fmaxf(sqrtf(ss), 1e-12f);
        float m = s * (1.0f / 96.0f);
        muv[gpix] = m;
        rsd[gpix] = rsqrtf(ss * (1.0f / 96.0f) - m * m + 1e-5f);
    }

    #pragma unroll
    for (int it = 0; it < 12; ++it) {
        int e = t + it * 256;
        int p = e / 96;
        int c = e - p * 96;
        xt[(b * HWPIX + p0 + p) * CH + c] = lds[c][p];
    }
}

// ---------------------------------------------------------------------------
// K2: one pixel per wave (round-3 proven grid: 2304 blocks x 256 thr,
//     ~32 waves/CU). Dot phase identical to the 78us round-3 version.
//     Top-8 via value-only max butterfly + ballot/ctz argmax (exact
//     lax.top_k tie-break: lowest window index among bit-equal maxima).
//     LN stats precomputed in k1. No __syncthreads (own row wave-private).
// ---------------------------------------------------------------------------
__global__ __launch_bounds__(256) void k2_knn(
    const float* __restrict__ xt, const float* __restrict__ invn,
    const float* __restrict__ muv, const float* __restrict__ rsd,
    const float* __restrict__ lnw, const float* __restrict__ lnb,
    float* __restrict__ enh)
{
    __shared__ float own[4][96];
    int t    = threadIdx.x;
    int wv   = t >> 6;
    int lane = t & 63;
    int gp   = blockIdx.x * 4 + wv;
    int b    = gp / HWPIX;
    int p    = gp - b * HWPIX;
    int py   = p / WW;
    int px   = p - py * WW;

    // wave-private staging of own feature row (broadcast source for dots)
    own[wv][lane] = xt[gp * CH + lane];
    if (lane < 32) own[wv][lane + 64] = xt[gp * CH + 64 + lane];
    float inp = invn[gp];
    float mu  = muv[gp];          // independent early loads
    float rs  = rsd[gp];

    // dot products: 3 window slots per lane (n = lane, lane+64, lane+128)
    float v0 = -2e9f, v1 = -2e9f, v2 = -2e9f;
    const float4* ov = (const float4*)(own[wv]);
    #pragma unroll
    for (int k = 0; k < 3; ++k) {
        int n = lane + 64 * k;
        float sim = -2e9f;
        if (n < WIN2) {
            int dy = n / WIN - HALF;
            int dx = n - (dy + HALF) * WIN - HALF;
            int ny = py + dy, nx = px + dx;
            if (ny >= 0 && ny < HH && nx >= 0 && nx < WW) {
                int q = b * HWPIX + ny * WW + nx;
                float inq = invn[q];
                const float4* qv = (const float4*)(xt + q * CH);
                float ax = 0.f, ay = 0.f, az = 0.f, aw = 0.f;
                #pragma unroll
                for (int c4 = 0; c4 < 24; ++c4) {
                    float4 a  = ov[c4];
                    float4 bb = qv[c4];
                    ax += a.x * bb.x; ay += a.y * bb.y;
                    az += a.z * bb.z; aw += a.w * bb.w;
                }
                sim = ((ax + ay) + (az + aw)) * inp * inq;
            } else {
                sim = NEGV;
            }
        }
        if (k == 0) v0 = sim; else if (k == 1) v1 = sim; else v2 = sim;
    }

    // top-8: value-only butterfly max + ballot/ctz argmax (exact tie-break)
    float tv[TOPK]; int tn[TOPK];
    #pragma unroll
    for (int r = 0; r < TOPK; ++r) {
        float m = fmaxf(fmaxf(v0, v1), v2);
        #pragma unroll
        for (int off = 1; off < 64; off <<= 1)
            m = fmaxf(m, __shfl_xor(m, off));
        // m is the exact wave max; find lowest window index holding it
        unsigned long long m0 = __ballot(v0 == m);
        unsigned long long m1 = __ballot(v1 == m);
        unsigned long long m2 = __ballot(v2 == m);
        int n;
        if (m0)      n = (int)__builtin_ctzll(m0);
        else if (m1) n = 64 + (int)__builtin_ctzll(m1);
        else         n = 128 + (int)__builtin_ctzll(m2);
        tv[r] = m; tn[r] = n;
        int kk = n >> 6, ll = n & 63;
        if (ll == lane) {
            if (kk == 0)      v0 = -2e9f;
            else if (kk == 1) v1 = -2e9f;
            else              v2 = -2e9f;
        }
    }

    // softmax weights + gather indices (wave-uniform)
    float wts[TOPK]; int qn[TOPK];
    float wsum = 0.f;
    #pragma unroll
    for (int r = 0; r < TOPK; ++r) {
        float e = expf(tv[r] - tv[0]);
        wts[r] = e; wsum += e;
        int n  = tn[r];
        int dy = n / WIN - HALF;
        int dx = n - (dy + HALF) * WIN - HALF;
        int gy = min(max(py + dy, 0), HH - 1);
        int gx = min(max(px + dx, 0), WW - 1);
        qn[r]  = b * HWPIX + gy * WW + gx;
    }
    float winv = 1.0f / wsum;

    // aggregate raw features + LayerNorm (stats from k1)
    float g1 = 0.f, g2 = 0.f;
    #pragma unroll
    for (int r = 0; r < TOPK; ++r) {
        const float* qrow = xt + qn[r] * CH;
        g1 += wts[r] * qrow[lane];
        g2 += wts[r] * qrow[64 + (lane & 31)];
    }
    g1 *= winv; g2 *= winv;

    float e1 = own[wv][lane];
    enh[gp * CH + lane] = g1 + (e1 - mu) * rs * lnw[lane] + lnb[lane];
    if (lane < 32) {
        int c = 64 + lane;
        float e2 = own[wv][c];
        enh[gp * CH + c] = g2 + (e2 - mu) * rs * lnw[c] + lnb[c];
    }
}

// ---------------------------------------------------------------------------
// K3: fused FFN, high-TLP version: 2304 blocks x 384 thr (6 waves), 4 px.
//     enh rows staged in LDS (el) -> ~50 VGPR -> ~30 waves/CU.
//     pix = lane&3, sub = lane>>2, grp = wv*16+sub in [0,96).
//     Phase A: 2 hidden units per lane (j = grp*2+jj).
//     Phase B: 1 output channel per lane (c = grp).
// ---------------------------------------------------------------------------
__global__ __launch_bounds__(384) void k3_ffn(
    const float* __restrict__ enh, const float* __restrict__ w1,
    const float* __restrict__ b1, const float* __restrict__ w2,
    const float* __restrict__ b2, float* __restrict__ out)
{
    __shared__ float hl[4][200];   // hidden tile, row stride 800 B
    __shared__ float el[4][100];   // enh tile,   row stride 400 B
    int g    = blockIdx.x;         // 2304 = 4 batches * 576 tiles
    int b    = g / 576;
    int p0   = (g % 576) * 4;
    int t    = threadIdx.x;
    int wv   = t >> 6;             // 0..5
    int lane = t & 63;
    int pix  = lane & 3;
    int sub  = lane >> 2;          // 0..15
    int grp  = wv * 16 + sub;      // 0..95

    // stage 4 enh rows (384 threads -> 384 elements, coalesced)
    {
        int r = t / 96, c = t - r * 96;
        el[r][c] = enh[(b * HWPIX + p0 + r) * CH + c];
    }
    __syncthreads();

    // phase A: 2 hidden units per lane
    const float4* w1v = (const float4*)w1;
    const float4* ep  = (const float4*)(&el[pix][0]);
    #pragma unroll
    for (int jj = 0; jj < 2; ++jj) {
        int j = grp * 2 + jj;
        float ax = 0.f, ay = 0.f, az = 0.f, aw = 0.f;
        #pragma unroll
        for (int c4 = 0; c4 < 24; ++c4) {
            float4 e4 = ep[c4];
            float4 w4 = w1v[j * 24 + c4];
            ax += e4.x * w4.x; ay += e4.y * w4.y;
            az += e4.z * w4.z; aw += e4.w * w4.w;
        }
        hl[pix][j] = fmaxf(((ax + ay) + (az + aw)) + b1[j], 0.f);
    }
    __syncthreads();

    // phase B: 1 output channel per lane (c = grp), 192-deep dot
    const float4* w2v = (const float4*)w2;
    const float4* hv4 = (const float4*)(&hl[pix][0]);
    int c = grp;
    float ax = 0.f, ay = 0.f, az = 0.f, aw = 0.f;
    #pragma unroll 8
    for (int j4 = 0; j4 < 48; ++j4) {
        float4 hv = hv4[j4];
        float4 q4 = w2v[c * 48 + j4];
        ax += hv.x * q4.x; ay += hv.y * q4.y;
        az += hv.z * q4.z; aw += hv.w * q4.w;
    }
    out[(b * CH + c) * HWPIX + p0 + pix] =
        el[pix][c] + ((ax + ay) + (az + aw)) + b2[c];
}

// ---------------------------------------------------------------------------
extern "C" void kernel_launch(void* const* d_in, const int* in_sizes, int n_in,
                              void* d_out, int out_size, void* d_ws, size_t ws_size,
                              hipStream_t stream)
{
    const float* x   = (const float*)d_in[0];
    const float* w1  = (const float*)d_in[1];
    const float* b1  = (const float*)d_in[2];
    const float* w2  = (const float*)d_in[3];
    const float* b2  = (const float*)d_in[4];
    const float* lnw = (const float*)d_in[5];
    const float* lnb = (const float*)d_in[6];
    float* out = (float*)d_out;

    // xt lives in d_out (exactly NPIX*CH floats): k1 writes it, k2 consumes it,
    // k3 then overwrites d_out with the final output (stream-ordered).
    float* xt = out;

    // workspace: enh + invn + muv + rsd = 912,384 floats = 3.65 MB
    float* ws   = (float*)d_ws;
    float* enh  = ws;                        // NPIX*96
    float* invn = enh + NPIX * CH;           // NPIX
    float* muv  = invn + NPIX;               // NPIX
    float* rsd  = muv + NPIX;                // NPIX

    hipLaunchKernelGGL(k1_prep, dim3(288), dim3(256), 0, stream,
                       x, xt, invn, muv, rsd);
    hipLaunchKernelGGL(k2_knn, dim3(NPIX / 4), dim3(256), 0, stream,
                       xt, invn, muv, rsd, lnw, lnb, enh);
    hipLaunchKernelGGL(k3_ffn, dim3(2304), dim3(384), 0, stream,
                       enh, w1, b1, w2, b2, out);
}

// Round 16
// 89.812 us; speedup vs baseline: 2.0440x; 1.4113x over previous
//
#include <hip/hip_runtime.h>
#include <math.h>

#define BATCH 4
#define CH    96
#define HH    48
#define WW    48
#define HWPIX (HH*WW)         // 2304
#define NPIX  (BATCH*HWPIX)   // 9216
#define WIN   13
#define WIN2  169
#define HALF  6
#define TOPK  8
#define NEGV  (-1000000000.0f)

// ---------------------------------------------------------------------------
// K1: x (B,C,H,W) -> xt2 CHUNK-MAJOR [(c/4)][pixel] float4 cells (in d_out),
//     + per-pixel invn / mu / rstd.
//     Chunk-major makes k2's window loads hit consecutive 16-B cells for
//     consecutive window pixels (the L1-scatter fix).
// ---------------------------------------------------------------------------
__global__ __launch_bounds__(256) void k1_prep(
    const float* __restrict__ x, float* __restrict__ xt2,
    float* __restrict__ invn, float* __restrict__ muv, float* __restrict__ rsd)
{
    __shared__ float lds[96][33];
    int bid = blockIdx.x;          // 288 = 4 batches * 72 tiles
    int b   = bid / 72;
    int p0  = (bid % 72) * 32;
    int t   = threadIdx.x;

    #pragma unroll
    for (int it = 0; it < 12; ++it) {
        int e = t + it * 256;
        int c = e >> 5;
        int p = e & 31;
        lds[c][p] = x[(b * CH + c) * HWPIX + p0 + p];
    }
    __syncthreads();

    if (t < 32) {
        float s = 0.f, ss = 0.f;
        #pragma unroll
        for (int c = 0; c < CH; ++c) { float v = lds[c][t]; s += v; ss += v * v; }
        int gpix = b * HWPIX + p0 + t;
        invn[gpix] = 1.0f / fmaxf(sqrtf(ss), 1e-12f);
        float m = s * (1.0f / 96.0f);
        muv[gpix] = m;
        rsd[gpix] = rsqrtf(ss * (1.0f / 96.0f) - m * m + 1e-5f);
    }

    // write chunk-major: 768 float4 cells (32 px * 24 chunks), 3 per thread
    float4* x4 = (float4*)xt2;
    #pragma unroll
    for (int it = 0; it < 3; ++it) {
        int i = t + it * 256;
        int p = i & 31;            // pixel within tile (fast -> coalesced)
        int s = i >> 5;            // chunk 0..23
        float4 v = make_float4(lds[4*s][p], lds[4*s+1][p],
                               lds[4*s+2][p], lds[4*s+3][p]);
        x4[s * NPIX + b * HWPIX + p0 + p] = v;
    }
}

// ---------------------------------------------------------------------------
// K2: one pixel per wave, 2304 blocks x 256 thr (proven TLP config).
//     All feature reads go through chunk-major xt2: a dot-phase load's 64
//     lanes now hit ~20 cache lines (13-px runs of consecutive cells)
//     instead of 64. Ballot top-8 (exact lax.top_k tie-break), LN stats
//     from k1. lane<24 owns chunk `lane` for staging/gather/enh (float4).
// ---------------------------------------------------------------------------
__global__ __launch_bounds__(256) void k2_knn(
    const float* __restrict__ xt2, const float* __restrict__ invn,
    const float* __restrict__ muv, const float* __restrict__ rsd,
    const float* __restrict__ lnw, const float* __restrict__ lnb,
    float* __restrict__ enh)
{
    __shared__ float own[4][96];
    int t    = threadIdx.x;
    int wv   = t >> 6;
    int lane = t & 63;
    int gp   = blockIdx.x * 4 + wv;
    int b    = gp / HWPIX;
    int p    = gp - b * HWPIX;
    int py   = p / WW;
    int px   = p - py * WW;
    const float4* x4 = (const float4*)xt2;

    // own-row staging: lanes 0..23 each fetch chunk `lane` (one 24-line inst)
    float4 ownv = make_float4(0.f, 0.f, 0.f, 0.f);
    if (lane < 24) {
        ownv = x4[lane * NPIX + gp];
        ((float4*)(own[wv]))[lane] = ownv;   // wave-private: no barrier
    }
    float inp = invn[gp];
    float mu  = muv[gp];
    float rs  = rsd[gp];

    // dot products: 3 window slots per lane (n = lane, lane+64, lane+128)
    float v0 = -2e9f, v1 = -2e9f, v2 = -2e9f;
    const float4* ov = (const float4*)(own[wv]);
    #pragma unroll
    for (int k = 0; k < 3; ++k) {
        int n = lane + 64 * k;
        float sim = -2e9f;
        if (n < WIN2) {
            int dy = n / WIN - HALF;
            int dx = n - (dy + HALF) * WIN - HALF;
            int ny = py + dy, nx = px + dx;
            if (ny >= 0 && ny < HH && nx >= 0 && nx < WW) {
                int q = b * HWPIX + ny * WW + nx;
                float inq = invn[q];
                const float4* rp = x4 + q;       // + s*NPIX per chunk
                float ax = 0.f, ay = 0.f, az = 0.f, aw = 0.f;
                #pragma unroll
                for (int s = 0; s < 24; ++s) {
                    float4 a  = ov[s];           // uniform -> LDS broadcast
                    float4 bb = rp[s * NPIX];    // consecutive lanes -> consecutive cells
                    ax += a.x * bb.x; ay += a.y * bb.y;
                    az += a.z * bb.z; aw += a.w * bb.w;
                }
                sim = ((ax + ay) + (az + aw)) * inp * inq;
            } else {
                sim = NEGV;
            }
        }
        if (k == 0) v0 = sim; else if (k == 1) v1 = sim; else v2 = sim;
    }

    // top-8: value-only butterfly max + ballot/ctz argmax (exact tie-break)
    float tv[TOPK]; int tn[TOPK];
    #pragma unroll
    for (int r = 0; r < TOPK; ++r) {
        float m = fmaxf(fmaxf(v0, v1), v2);
        #pragma unroll
        for (int off = 1; off < 64; off <<= 1)
            m = fmaxf(m, __shfl_xor(m, off));
        unsigned long long m0 = __ballot(v0 == m);
        unsigned long long m1 = __ballot(v1 == m);
        unsigned long long m2 = __ballot(v2 == m);
        int n;
        if (m0)      n = (int)__builtin_ctzll(m0);
        else if (m1) n = 64 + (int)__builtin_ctzll(m1);
        else         n = 128 + (int)__builtin_ctzll(m2);
        tv[r] = m; tn[r] = n;
        int kk = n >> 6, ll = n & 63;
        if (ll == lane) {
            if (kk == 0)      v0 = -2e9f;
            else if (kk == 1) v1 = -2e9f;
            else              v2 = -2e9f;
        }
    }

    // softmax weights + gather indices (wave-uniform)
    float wts[TOPK]; int qn[TOPK];
    float wsum = 0.f;
    #pragma unroll
    for (int r = 0; r < TOPK; ++r) {
        float e = expf(tv[r] - tv[0]);
        wts[r] = e; wsum += e;
        int n  = tn[r];
        int dy = n / WIN - HALF;
        int dx = n - (dy + HALF) * WIN - HALF;
        int gy = min(max(py + dy, 0), HH - 1);
        int gx = min(max(px + dx, 0), WW - 1);
        qn[r]  = b * HWPIX + gy * WW + gx;
    }
    float winv = 1.0f / wsum;

    // gather + LayerNorm + enh store, chunk-per-lane (lanes 0..23, float4)
    if (lane < 24) {
        const float4* base = x4 + lane * NPIX;
        float4 g = make_float4(0.f, 0.f, 0.f, 0.f);
        #pragma unroll
        for (int r = 0; r < TOPK; ++r) {
            float4 f = base[qn[r]];
            float w = wts[r];
            g.x += w * f.x; g.y += w * f.y;
            g.z += w * f.z; g.w += w * f.w;
        }
        float4 lw = ((const float4*)lnw)[lane];
        float4 lb = ((const float4*)lnb)[lane];
        float4 e;
        e.x = g.x * winv + (ownv.x - mu) * rs * lw.x + lb.x;
        e.y = g.y * winv + (ownv.y - mu) * rs * lw.y + lb.y;
        e.z = g.z * winv + (ownv.z - mu) * rs * lw.z + lb.z;
        e.w = g.w * winv + (ownv.w - mu) * rs * lw.w + lb.w;
        ((float4*)(enh + gp * CH))[lane] = e;    // coalesced 384-B store
    }
}

// ---------------------------------------------------------------------------
// K3: fused FFN, 2304 blocks x 384 thr (6 waves), 4 px (round-15, passing).
// ---------------------------------------------------------------------------
__global__ __launch_bounds__(384) void k3_ffn(
    const float* __restrict__ enh, const float* __restrict__ w1,
    const float* __restrict__ b1, const float* __restrict__ w2,
    const float* __restrict__ b2, float* __restrict__ out)
{
    __shared__ float hl[4][200];   // hidden tile, row stride 800 B
    __shared__ float el[4][100];   // enh tile,   row stride 400 B
    int g    = blockIdx.x;         // 2304 = 4 batches * 576 tiles
    int b    = g / 576;
    int p0   = (g % 576) * 4;
    int t    = threadIdx.x;
    int wv   = t >> 6;             // 0..5
    int lane = t & 63;
    int pix  = lane & 3;
    int sub  = lane >> 2;          // 0..15
    int grp  = wv * 16 + sub;      // 0..95

    // stage 4 enh rows (384 threads -> 384 elements, coalesced)
    {
        int r = t / 96, c = t - r * 96;
        el[r][c] = enh[(b * HWPIX + p0 + r) * CH + c];
    }
    __syncthreads();

    // phase A: 2 hidden units per lane
    const float4* w1v = (const float4*)w1;
    const float4* ep  = (const float4*)(&el[pix][0]);
    #pragma unroll
    for (int jj = 0; jj < 2; ++jj) {
        int j = grp * 2 + jj;
        float ax = 0.f, ay = 0.f, az = 0.f, aw = 0.f;
        #pragma unroll
        for (int c4 = 0; c4 < 24; ++c4) {
            float4 e4 = ep[c4];
            float4 w4 = w1v[j * 24 + c4];
            ax += e4.x * w4.x; ay += e4.y * w4.y;
            az += e4.z * w4.z; aw += e4.w * w4.w;
        }
        hl[pix][j] = fmaxf(((ax + ay) + (az + aw)) + b1[j], 0.f);
    }
    __syncthreads();

    // phase B: 1 output channel per lane (c = grp), 192-deep dot
    const float4* w2v = (const float4*)w2;
    const float4* hv4 = (const float4*)(&hl[pix][0]);
    int c = grp;
    float ax = 0.f, ay = 0.f, az = 0.f, aw = 0.f;
    #pragma unroll 8
    for (int j4 = 0; j4 < 48; ++j4) {
        float4 hv = hv4[j4];
        float4 q4 = w2v[c * 48 + j4];
        ax += hv.x * q4.x; ay += hv.y * q4.y;
        az += hv.z * q4.z; aw += hv.w * q4.w;
    }
    out[(b * CH + c) * HWPIX + p0 + pix] =
        el[pix][c] + ((ax + ay) + (az + aw)) + b2[c];
}

// ---------------------------------------------------------------------------
extern "C" void kernel_launch(void* const* d_in, const int* in_sizes, int n_in,
                              void* d_out, int out_size, void* d_ws, size_t ws_size,
                              hipStream_t stream)
{
    const float* x   = (const float*)d_in[0];
    const float* w1  = (const float*)d_in[1];
    const float* b1  = (const float*)d_in[2];
    const float* w2  = (const float*)d_in[3];
    const float* b2  = (const float*)d_in[4];
    const float* lnw = (const float*)d_in[5];
    const float* lnb = (const float*)d_in[6];
    float* out = (float*)d_out;

    // xt2 (chunk-major features) lives in d_out (exactly NPIX*CH floats):
    // k1 writes it, k2 consumes it, k3 then overwrites d_out with the output.
    float* xt2 = out;

    // workspace: enh + invn + muv + rsd = 912,384 floats = 3.65 MB (proven)
    float* ws   = (float*)d_ws;
    float* enh  = ws;                        // NPIX*96
    float* invn = enh + NPIX * CH;           // NPIX
    float* muv  = invn + NPIX;               // NPIX
    float* rsd  = muv + NPIX;                // NPIX

    hipLaunchKernelGGL(k1_prep, dim3(288), dim3(256), 0, stream,
                       x, xt2, invn, muv, rsd);
    hipLaunchKernelGGL(k2_knn, dim3(NPIX / 4), dim3(256), 0, stream,
                       xt2, invn, muv, rsd, lnw, lnb, enh);
    hipLaunchKernelGGL(k3_ffn, dim3(2304), dim3(384), 0, stream,
                       enh, w1, b1, w2, b2, out);
}

// Round 17
// 85.134 us; speedup vs baseline: 2.1563x; 1.0550x over previous
//
#include <hip/hip_runtime.h>
#include <math.h>

#define BATCH 4
#define CH    96
#define HH    48
#define WW    48
#define HWPIX (HH*WW)         // 2304
#define NPIX  (BATCH*HWPIX)   // 9216
#define WIN   13
#define WIN2  169
#define HALF  6
#define TOPK  8
#define NEGV  (-1000000000.0f)

// ---------------------------------------------------------------------------
// K0: transpose weights once: w1 [192][96] -> w1T [96][192],
//     w2 [96][192] -> w2T [192][96]. 36 blocks x 256 thr.
//     Makes k3's weight loads lane-consecutive (4 lines/inst instead of 16).
// ---------------------------------------------------------------------------
__global__ __launch_bounds__(256) void k0_wt(
    const float* __restrict__ w1, const float* __restrict__ w2,
    float* __restrict__ w1T, float* __restrict__ w2T)
{
    __shared__ float tile[32][33];
    int bid = blockIdx.x;          // 0..17: w1 (6x3 tiles), 18..35: w2 (3x6)
    const float* src; float* dst; int R, C, tr, tc;
    if (bid < 18) { src = w1; dst = w1T; R = 192; C = 96;  tr = bid / 3; tc = bid % 3; }
    else { int b2 = bid - 18; src = w2; dst = w2T; R = 96; C = 192; tr = b2 / 6; tc = b2 % 6; }
    int r0 = tr * 32, c0 = tc * 32;
    int tx = threadIdx.x & 31, ty = threadIdx.x >> 5;   // ty 0..7

    #pragma unroll
    for (int i = 0; i < 4; ++i) {
        int r = ty + i * 8;
        tile[r][tx] = src[(r0 + r) * C + c0 + tx];
    }
    __syncthreads();
    #pragma unroll
    for (int i = 0; i < 4; ++i) {
        int r = ty + i * 8;
        dst[(c0 + r) * R + r0 + tx] = tile[tx][r];   // dst[c][r] = src[r][c]
    }
}

// ---------------------------------------------------------------------------
// K1: x (B,C,H,W) -> xt2 CHUNK-MAJOR [(c/4)][pixel] float4 cells (in d_out),
//     + per-pixel invn / mu / rstd. (round-16, passing)
// ---------------------------------------------------------------------------
__global__ __launch_bounds__(256) void k1_prep(
    const float* __restrict__ x, float* __restrict__ xt2,
    float* __restrict__ invn, float* __restrict__ muv, float* __restrict__ rsd)
{
    __shared__ float lds[96][33];
    int bid = blockIdx.x;          // 288 = 4 batches * 72 tiles
    int b   = bid / 72;
    int p0  = (bid % 72) * 32;
    int t   = threadIdx.x;

    #pragma unroll
    for (int it = 0; it < 12; ++it) {
        int e = t + it * 256;
        int c = e >> 5;
        int p = e & 31;
        lds[c][p] = x[(b * CH + c) * HWPIX + p0 + p];
    }
    __syncthreads();

    if (t < 32) {
        float s = 0.f, ss = 0.f;
        #pragma unroll
        for (int c = 0; c < CH; ++c) { float v = lds[c][t]; s += v; ss += v * v; }
        int gpix = b * HWPIX + p0 + t;
        invn[gpix] = 1.0f / fmaxf(sqrtf(ss), 1e-12f);
        float m = s * (1.0f / 96.0f);
        muv[gpix] = m;
        rsd[gpix] = rsqrtf(ss * (1.0f / 96.0f) - m * m + 1e-5f);
    }

    float4* x4 = (float4*)xt2;
    #pragma unroll
    for (int it = 0; it < 3; ++it) {
        int i = t + it * 256;
        int p = i & 31;
        int s = i >> 5;
        float4 v = make_float4(lds[4*s][p], lds[4*s+1][p],
                               lds[4*s+2][p], lds[4*s+3][p]);
        x4[s * NPIX + b * HWPIX + p0 + p] = v;
    }
}

// ---------------------------------------------------------------------------
// K2: one pixel per wave, 2304 blocks x 256 thr, chunk-major reads,
//     ballot top-8, LN stats from k1. (round-16, passing)
// ---------------------------------------------------------------------------
__global__ __launch_bounds__(256) void k2_knn(
    const float* __restrict__ xt2, const float* __restrict__ invn,
    const float* __restrict__ muv, const float* __restrict__ rsd,
    const float* __restrict__ lnw, const float* __restrict__ lnb,
    float* __restrict__ enh)
{
    __shared__ float own[4][96];
    int t    = threadIdx.x;
    int wv   = t >> 6;
    int lane = t & 63;
    int gp   = blockIdx.x * 4 + wv;
    int b    = gp / HWPIX;
    int p    = gp - b * HWPIX;
    int py   = p / WW;
    int px   = p - py * WW;
    const float4* x4 = (const float4*)xt2;

    float4 ownv = make_float4(0.f, 0.f, 0.f, 0.f);
    if (lane < 24) {
        ownv = x4[lane * NPIX + gp];
        ((float4*)(own[wv]))[lane] = ownv;
    }
    float inp = invn[gp];
    float mu  = muv[gp];
    float rs  = rsd[gp];

    float v0 = -2e9f, v1 = -2e9f, v2 = -2e9f;
    const float4* ov = (const float4*)(own[wv]);
    #pragma unroll
    for (int k = 0; k < 3; ++k) {
        int n = lane + 64 * k;
        float sim = -2e9f;
        if (n < WIN2) {
            int dy = n / WIN - HALF;
            int dx = n - (dy + HALF) * WIN - HALF;
            int ny = py + dy, nx = px + dx;
            if (ny >= 0 && ny < HH && nx >= 0 && nx < WW) {
                int q = b * HWPIX + ny * WW + nx;
                float inq = invn[q];
                const float4* rp = x4 + q;
                float ax = 0.f, ay = 0.f, az = 0.f, aw = 0.f;
                #pragma unroll
                for (int s = 0; s < 24; ++s) {
                    float4 a  = ov[s];
                    float4 bb = rp[s * NPIX];
                    ax += a.x * bb.x; ay += a.y * bb.y;
                    az += a.z * bb.z; aw += a.w * bb.w;
                }
                sim = ((ax + ay) + (az + aw)) * inp * inq;
            } else {
                sim = NEGV;
            }
        }
        if (k == 0) v0 = sim; else if (k == 1) v1 = sim; else v2 = sim;
    }

    float tv[TOPK]; int tn[TOPK];
    #pragma unroll
    for (int r = 0; r < TOPK; ++r) {
        float m = fmaxf(fmaxf(v0, v1), v2);
        #pragma unroll
        for (int off = 1; off < 64; off <<= 1)
            m = fmaxf(m, __shfl_xor(m, off));
        unsigned long long m0 = __ballot(v0 == m);
        unsigned long long m1 = __ballot(v1 == m);
        unsigned long long m2 = __ballot(v2 == m);
        int n;
        if (m0)      n = (int)__builtin_ctzll(m0);
        else if (m1) n = 64 + (int)__builtin_ctzll(m1);
        else         n = 128 + (int)__builtin_ctzll(m2);
        tv[r] = m; tn[r] = n;
        int kk = n >> 6, ll = n & 63;
        if (ll == lane) {
            if (kk == 0)      v0 = -2e9f;
            else if (kk == 1) v1 = -2e9f;
            else              v2 = -2e9f;
        }
    }

    float wts[TOPK]; int qn[TOPK];
    float wsum = 0.f;
    #pragma unroll
    for (int r = 0; r < TOPK; ++r) {
        float e = expf(tv[r] - tv[0]);
        wts[r] = e; wsum += e;
        int n  = tn[r];
        int dy = n / WIN - HALF;
        int dx = n - (dy + HALF) * WIN - HALF;
        int gy = min(max(py + dy, 0), HH - 1);
        int gx = min(max(px + dx, 0), WW - 1);
        qn[r]  = b * HWPIX + gy * WW + gx;
    }
    float winv = 1.0f / wsum;

    if (lane < 24) {
        const float4* base = x4 + lane * NPIX;
        float4 g = make_float4(0.f, 0.f, 0.f, 0.f);
        #pragma unroll
        for (int r = 0; r < TOPK; ++r) {
            float4 f = base[qn[r]];
            float w = wts[r];
            g.x += w * f.x; g.y += w * f.y;
            g.z += w * f.z; g.w += w * f.w;
        }
        float4 lw = ((const float4*)lnw)[lane];
        float4 lb = ((const float4*)lnb)[lane];
        float4 e;
        e.x = g.x * winv + (ownv.x - mu) * rs * lw.x + lb.x;
        e.y = g.y * winv + (ownv.y - mu) * rs * lw.y + lb.y;
        e.z = g.z * winv + (ownv.z - mu) * rs * lw.z + lb.z;
        e.w = g.w * winv + (ownv.w - mu) * rs * lw.w + lb.w;
        ((float4*)(enh + gp * CH))[lane] = e;
    }
}

// ---------------------------------------------------------------------------
// K3: fused FFN with TRANSPOSED weights (lane = output index -> coalesced).
//     8 px/block, 1152 blocks x 384 thr.
//     Phase A: j = t%192, pg = t/192; pixels {pg, pg+2, pg+4, pg+6}.
//     Phase B: c = t%96,  qg = t/96;  pixels {qg, qg+4}.
// ---------------------------------------------------------------------------
__global__ __launch_bounds__(384) void k3_ffn(
    const float* __restrict__ enh, const float* __restrict__ w1T,
    const float* __restrict__ b1, const float* __restrict__ w2T,
    const float* __restrict__ b2, float* __restrict__ out)
{
    __shared__ float el[8][100];   // 400 B rows (16B-aligned)
    __shared__ float hl[8][200];   // 800 B rows
    int g  = blockIdx.x;           // 1152 = 4 batches * 288 tiles
    int b  = g / 288;
    int p0 = (g % 288) * 8;
    int t  = threadIdx.x;

    // stage 8 enh rows (768 floats, 2/thread, coalesced)
    #pragma unroll
    for (int i = 0; i < 2; ++i) {
        int e = t + i * 384;
        int r = e / 96, c = e - r * 96;
        el[r][c] = enh[(b * HWPIX + p0 + r) * CH + c];
    }
    __syncthreads();

    // phase A: one hidden unit j for 4 pixels
    {
        int j  = (t >= 192) ? t - 192 : t;
        int pg = (t >= 192) ? 1 : 0;
        const float4* e0 = (const float4*)(&el[pg    ][0]);
        const float4* e1 = (const float4*)(&el[pg + 2][0]);
        const float4* e2 = (const float4*)(&el[pg + 4][0]);
        const float4* e3 = (const float4*)(&el[pg + 6][0]);
        float a0 = 0.f, a1 = 0.f, a2 = 0.f, a3 = 0.f;
        #pragma unroll 6
        for (int c4 = 0; c4 < 24; ++c4) {
            float wa = w1T[(4*c4 + 0) * 192 + j];   // lane-consecutive j
            float wb = w1T[(4*c4 + 1) * 192 + j];
            float wc = w1T[(4*c4 + 2) * 192 + j];
            float wd = w1T[(4*c4 + 3) * 192 + j];
            float4 v0 = e0[c4], v1 = e1[c4], v2 = e2[c4], v3 = e3[c4];
            a0 += v0.x*wa + v0.y*wb + v0.z*wc + v0.w*wd;
            a1 += v1.x*wa + v1.y*wb + v1.z*wc + v1.w*wd;
            a2 += v2.x*wa + v2.y*wb + v2.z*wc + v2.w*wd;
            a3 += v3.x*wa + v3.y*wb + v3.z*wc + v3.w*wd;
        }
        float bj = b1[j];
        hl[pg    ][j] = fmaxf(a0 + bj, 0.f);
        hl[pg + 2][j] = fmaxf(a1 + bj, 0.f);
        hl[pg + 4][j] = fmaxf(a2 + bj, 0.f);
        hl[pg + 6][j] = fmaxf(a3 + bj, 0.f);
    }
    __syncthreads();

    // phase B: one output channel c for 2 pixels
    {
        int c  = t % 96;
        int qg = t / 96;           // 0..3
        const float4* h0 = (const float4*)(&hl[qg    ][0]);
        const float4* h1 = (const float4*)(&hl[qg + 4][0]);
        float s0 = 0.f, s1 = 0.f;
        #pragma unroll 6
        for (int j4 = 0; j4 < 48; ++j4) {
            float wa = w2T[(4*j4 + 0) * 96 + c];    // lane-consecutive c
            float wb = w2T[(4*j4 + 1) * 96 + c];
            float wc = w2T[(4*j4 + 2) * 96 + c];
            float wd = w2T[(4*j4 + 3) * 96 + c];
            float4 u0 = h0[j4], u1 = h1[j4];
            s0 += u0.x*wa + u0.y*wb + u0.z*wc + u0.w*wd;
            s1 += u1.x*wa + u1.y*wb + u1.z*wc + u1.w*wd;
        }
        float bc = b2[c];
        out[(b * CH + c) * HWPIX + p0 + qg    ] = el[qg    ][c] + s0 + bc;
        out[(b * CH + c) * HWPIX + p0 + qg + 4] = el[qg + 4][c] + s1 + bc;
    }
}

// ---------------------------------------------------------------------------
extern "C" void kernel_launch(void* const* d_in, const int* in_sizes, int n_in,
                              void* d_out, int out_size, void* d_ws, size_t ws_size,
                              hipStream_t stream)
{
    const float* x   = (const float*)d_in[0];
    const float* w1  = (const float*)d_in[1];
    const float* b1  = (const float*)d_in[2];
    const float* w2  = (const float*)d_in[3];
    const float* b2  = (const float*)d_in[4];
    const float* lnw = (const float*)d_in[5];
    const float* lnb = (const float*)d_in[6];
    float* out = (float*)d_out;

    // xt2 (chunk-major features) lives in d_out: k1 writes, k2 consumes,
    // k3 then overwrites d_out with the final output (stream-ordered).
    float* xt2 = out;

    // workspace: enh + invn + muv + rsd + w1T + w2T = 949,248 floats = 3.80 MB
    float* ws   = (float*)d_ws;
    float* enh  = ws;                        // NPIX*96
    float* invn = enh + NPIX * CH;           // NPIX
    float* muv  = invn + NPIX;               // NPIX
    float* rsd  = muv + NPIX;                // NPIX
    float* w1T  = rsd + NPIX;                // 96*192 = 18432
    float* w2T  = w1T + 192 * 96;            // 192*96 = 18432

    hipLaunchKernelGGL(k0_wt, dim3(36), dim3(256), 0, stream,
                       w1, w2, w1T, w2T);
    hipLaunchKernelGGL(k1_prep, dim3(288), dim3(256), 0, stream,
                       x, xt2, invn, muv, rsd);
    hipLaunchKernelGGL(k2_knn, dim3(NPIX / 4), dim3(256), 0, stream,
                       xt2, invn, muv, rsd, lnw, lnb, enh);
    hipLaunchKernelGGL(k3_ffn, dim3(1152), dim3(384), 0, stream,
                       enh, w1T, b1, w2T, b2, out);
}

// Round 18
// 76.353 us; speedup vs baseline: 2.4043x; 1.1150x over previous
//
#include <hip/hip_runtime.h>
#include <math.h>

#define BATCH 4
#define CH    96
#define HH    48
#define WW    48
#define HWPIX (HH*WW)         // 2304
#define NPIX  (BATCH*HWPIX)   // 9216
#define WIN   13
#define WIN2  169
#define HALF  6
#define TOPK  8
#define NEGV  (-1000000000.0f)

// ---------------------------------------------------------------------------
// K0: transpose weights once: w1 [192][96] -> w1T [96][192],
//     w2 [96][192] -> w2T [192][96]. 36 blocks x 256 thr. (passing)
// ---------------------------------------------------------------------------
__global__ __launch_bounds__(256) void k0_wt(
    const float* __restrict__ w1, const float* __restrict__ w2,
    float* __restrict__ w1T, float* __restrict__ w2T)
{
    __shared__ float tile[32][33];
    int bid = blockIdx.x;          // 0..17: w1 (6x3 tiles), 18..35: w2 (3x6)
    const float* src; float* dst; int R, C, tr, tc;
    if (bid < 18) { src = w1; dst = w1T; R = 192; C = 96;  tr = bid / 3; tc = bid % 3; }
    else { int b2 = bid - 18; src = w2; dst = w2T; R = 96; C = 192; tr = b2 / 6; tc = b2 % 6; }
    int r0 = tr * 32, c0 = tc * 32;
    int tx = threadIdx.x & 31, ty = threadIdx.x >> 5;   // ty 0..7

    #pragma unroll
    for (int i = 0; i < 4; ++i) {
        int r = ty + i * 8;
        tile[r][tx] = src[(r0 + r) * C + c0 + tx];
    }
    __syncthreads();
    #pragma unroll
    for (int i = 0; i < 4; ++i) {
        int r = ty + i * 8;
        dst[(c0 + r) * R + r0 + tx] = tile[tx][r];   // dst[c][r] = src[r][c]
    }
}

// ---------------------------------------------------------------------------
// K1: x (B,C,H,W) -> xt2 CHUNK-MAJOR [(c/4)][pixel] float4 cells (in d_out),
//     + per-pixel invn / mu / rstd. (passing)
// ---------------------------------------------------------------------------
__global__ __launch_bounds__(256) void k1_prep(
    const float* __restrict__ x, float* __restrict__ xt2,
    float* __restrict__ invn, float* __restrict__ muv, float* __restrict__ rsd)
{
    __shared__ float lds[96][33];
    int bid = blockIdx.x;          // 288 = 4 batches * 72 tiles
    int b   = bid / 72;
    int p0  = (bid % 72) * 32;
    int t   = threadIdx.x;

    #pragma unroll
    for (int it = 0; it < 12; ++it) {
        int e = t + it * 256;
        int c = e >> 5;
        int p = e & 31;
        lds[c][p] = x[(b * CH + c) * HWPIX + p0 + p];
    }
    __syncthreads();

    if (t < 32) {
        float s = 0.f, ss = 0.f;
        #pragma unroll
        for (int c = 0; c < CH; ++c) { float v = lds[c][t]; s += v; ss += v * v; }
        int gpix = b * HWPIX + p0 + t;
        invn[gpix] = 1.0f / fmaxf(sqrtf(ss), 1e-12f);
        float m = s * (1.0f / 96.0f);
        muv[gpix] = m;
        rsd[gpix] = rsqrtf(ss * (1.0f / 96.0f) - m * m + 1e-5f);
    }

    float4* x4 = (float4*)xt2;
    #pragma unroll
    for (int it = 0; it < 3; ++it) {
        int i = t + it * 256;
        int p = i & 31;
        int s = i >> 5;
        float4 v = make_float4(lds[4*s][p], lds[4*s+1][p],
                               lds[4*s+2][p], lds[4*s+3][p]);
        x4[s * NPIX + b * HWPIX + p0 + p] = v;
    }
}

// ---------------------------------------------------------------------------
// K2: one pixel per wave, 2304 blocks x 256 thr, chunk-major reads,
//     ballot top-8, LN stats from k1. (passing)
// ---------------------------------------------------------------------------
__global__ __launch_bounds__(256) void k2_knn(
    const float* __restrict__ xt2, const float* __restrict__ invn,
    const float* __restrict__ muv, const float* __restrict__ rsd,
    const float* __restrict__ lnw, const float* __restrict__ lnb,
    float* __restrict__ enh)
{
    __shared__ float own[4][96];
    int t    = threadIdx.x;
    int wv   = t >> 6;
    int lane = t & 63;
    int gp   = blockIdx.x * 4 + wv;
    int b    = gp / HWPIX;
    int p    = gp - b * HWPIX;
    int py   = p / WW;
    int px   = p - py * WW;
    const float4* x4 = (const float4*)xt2;

    float4 ownv = make_float4(0.f, 0.f, 0.f, 0.f);
    if (lane < 24) {
        ownv = x4[lane * NPIX + gp];
        ((float4*)(own[wv]))[lane] = ownv;
    }
    float inp = invn[gp];
    float mu  = muv[gp];
    float rs  = rsd[gp];

    float v0 = -2e9f, v1 = -2e9f, v2 = -2e9f;
    const float4* ov = (const float4*)(own[wv]);
    #pragma unroll
    for (int k = 0; k < 3; ++k) {
        int n = lane + 64 * k;
        float sim = -2e9f;
        if (n < WIN2) {
            int dy = n / WIN - HALF;
            int dx = n - (dy + HALF) * WIN - HALF;
            int ny = py + dy, nx = px + dx;
            if (ny >= 0 && ny < HH && nx >= 0 && nx < WW) {
                int q = b * HWPIX + ny * WW + nx;
                float inq = invn[q];
                const float4* rp = x4 + q;
                float ax = 0.f, ay = 0.f, az = 0.f, aw = 0.f;
                #pragma unroll
                for (int s = 0; s < 24; ++s) {
                    float4 a  = ov[s];
                    float4 bb = rp[s * NPIX];
                    ax += a.x * bb.x; ay += a.y * bb.y;
                    az += a.z * bb.z; aw += a.w * bb.w;
                }
                sim = ((ax + ay) + (az + aw)) * inp * inq;
            } else {
                sim = NEGV;
            }
        }
        if (k == 0) v0 = sim; else if (k == 1) v1 = sim; else v2 = sim;
    }

    float tv[TOPK]; int tn[TOPK];
    #pragma unroll
    for (int r = 0; r < TOPK; ++r) {
        float m = fmaxf(fmaxf(v0, v1), v2);
        #pragma unroll
        for (int off = 1; off < 64; off <<= 1)
            m = fmaxf(m, __shfl_xor(m, off));
        unsigned long long m0 = __ballot(v0 == m);
        unsigned long long m1 = __ballot(v1 == m);
        unsigned long long m2 = __ballot(v2 == m);
        int n;
        if (m0)      n = (int)__builtin_ctzll(m0);
        else if (m1) n = 64 + (int)__builtin_ctzll(m1);
        else         n = 128 + (int)__builtin_ctzll(m2);
        tv[r] = m; tn[r] = n;
        int kk = n >> 6, ll = n & 63;
        if (ll == lane) {
            if (kk == 0)      v0 = -2e9f;
            else if (kk == 1) v1 = -2e9f;
            else              v2 = -2e9f;
        }
    }

    float wts[TOPK]; int qn[TOPK];
    float wsum = 0.f;
    #pragma unroll
    for (int r = 0; r < TOPK; ++r) {
        float e = expf(tv[r] - tv[0]);
        wts[r] = e; wsum += e;
        int n  = tn[r];
        int dy = n / WIN - HALF;
        int dx = n - (dy + HALF) * WIN - HALF;
        int gy = min(max(py + dy, 0), HH - 1);
        int gx = min(max(px + dx, 0), WW - 1);
        qn[r]  = b * HWPIX + gy * WW + gx;
    }
    float winv = 1.0f / wsum;

    if (lane < 24) {
        const float4* base = x4 + lane * NPIX;
        float4 g = make_float4(0.f, 0.f, 0.f, 0.f);
        #pragma unroll
        for (int r = 0; r < TOPK; ++r) {
            float4 f = base[qn[r]];
            float w = wts[r];
            g.x += w * f.x; g.y += w * f.y;
            g.z += w * f.z; g.w += w * f.w;
        }
        float4 lw = ((const float4*)lnw)[lane];
        float4 lb = ((const float4*)lnb)[lane];
        float4 e;
        e.x = g.x * winv + (ownv.x - mu) * rs * lw.x + lb.x;
        e.y = g.y * winv + (ownv.y - mu) * rs * lw.y + lb.y;
        e.z = g.z * winv + (ownv.z - mu) * rs * lw.z + lb.z;
        e.w = g.w * winv + (ownv.w - mu) * rs * lw.w + lb.w;
        ((float4*)(enh + gp * CH))[lane] = e;
    }
}

// ---------------------------------------------------------------------------
// K3: fused FFN, high-occupancy low-duplication version.
//     2304 blocks x 192 thr, 4 block-uniform pixels per block.
//     Phase A: thread = hidden unit j (weights 1x/block, lane-consecutive);
//              activations read as wave-UNIFORM loads from enh (SMEM path).
//     Phase B: threads 0..95, thread = channel c, 4 acc (weights 1x/block).
//     LDS: hl[4][200] = 3.2 KB -> ~9 blocks/CU resident.
// ---------------------------------------------------------------------------
__global__ __launch_bounds__(192) void k3_ffn(
    const float* __restrict__ enh, const float* __restrict__ w1T,
    const float* __restrict__ b1, const float* __restrict__ w2T,
    const float* __restrict__ b2, float* __restrict__ out)
{
    __shared__ float hl[4][200];   // 800 B rows, 16B-aligned
    int g  = blockIdx.x;           // 2304 = 4 batches * 576 tiles
    int b  = g / 576;
    int p0 = (g % 576) * 4;
    int t  = threadIdx.x;

    // phase A: one hidden unit j for 4 block-uniform pixels
    {
        int j = t;                 // 0..191
        const float4* e0 = (const float4*)(enh + (b * HWPIX + p0 + 0) * CH);
        const float4* e1 = (const float4*)(enh + (b * HWPIX + p0 + 1) * CH);
        const float4* e2 = (const float4*)(enh + (b * HWPIX + p0 + 2) * CH);
        const float4* e3 = (const float4*)(enh + (b * HWPIX + p0 + 3) * CH);
        float a0 = 0.f, a1 = 0.f, a2 = 0.f, a3 = 0.f;
        #pragma unroll 6
        for (int c4 = 0; c4 < 24; ++c4) {
            float wa = w1T[(4*c4 + 0) * 192 + j];   // lane-consecutive j
            float wb = w1T[(4*c4 + 1) * 192 + j];
            float wc = w1T[(4*c4 + 2) * 192 + j];
            float wd = w1T[(4*c4 + 3) * 192 + j];
            float4 v0 = e0[c4];                     // block-uniform -> s_load
            float4 v1 = e1[c4];
            float4 v2 = e2[c4];
            float4 v3 = e3[c4];
            a0 += v0.x*wa + v0.y*wb + v0.z*wc + v0.w*wd;
            a1 += v1.x*wa + v1.y*wb + v1.z*wc + v1.w*wd;
            a2 += v2.x*wa + v2.y*wb + v2.z*wc + v2.w*wd;
            a3 += v3.x*wa + v3.y*wb + v3.z*wc + v3.w*wd;
        }
        float bj = b1[j];
        hl[0][j] = fmaxf(a0 + bj, 0.f);
        hl[1][j] = fmaxf(a1 + bj, 0.f);
        hl[2][j] = fmaxf(a2 + bj, 0.f);
        hl[3][j] = fmaxf(a3 + bj, 0.f);
    }
    __syncthreads();

    // phase B: threads 0..95: one channel c, all 4 pixels (weights 1x)
    if (t < 96) {
        int c = t;
        const float4* h0 = (const float4*)(&hl[0][0]);
        const float4* h1 = (const float4*)(&hl[1][0]);
        const float4* h2 = (const float4*)(&hl[2][0]);
        const float4* h3 = (const float4*)(&hl[3][0]);
        float s0 = 0.f, s1 = 0.f, s2 = 0.f, s3 = 0.f;
        #pragma unroll 6
        for (int j4 = 0; j4 < 48; ++j4) {
            float wa = w2T[(4*j4 + 0) * 96 + c];    // lane-consecutive c
            float wb = w2T[(4*j4 + 1) * 96 + c];
            float wc = w2T[(4*j4 + 2) * 96 + c];
            float wd = w2T[(4*j4 + 3) * 96 + c];
            float4 u0 = h0[j4], u1 = h1[j4], u2 = h2[j4], u3 = h3[j4];
            s0 += u0.x*wa + u0.y*wb + u0.z*wc + u0.w*wd;
            s1 += u1.x*wa + u1.y*wb + u1.z*wc + u1.w*wd;
            s2 += u2.x*wa + u2.y*wb + u2.z*wc + u2.w*wd;
            s3 += u3.x*wa + u3.y*wb + u3.z*wc + u3.w*wd;
        }
        float bc = b2[c];
        out[(b * CH + c) * HWPIX + p0 + 0] =
            enh[(b * HWPIX + p0 + 0) * CH + c] + s0 + bc;
        out[(b * CH + c) * HWPIX + p0 + 1] =
            enh[(b * HWPIX + p0 + 1) * CH + c] + s1 + bc;
        out[(b * CH + c) * HWPIX + p0 + 2] =
            enh[(b * HWPIX + p0 + 2) * CH + c] + s2 + bc;
        out[(b * CH + c) * HWPIX + p0 + 3] =
            enh[(b * HWPIX + p0 + 3) * CH + c] + s3 + bc;
    }
}

// ---------------------------------------------------------------------------
extern "C" void kernel_launch(void* const* d_in, const int* in_sizes, int n_in,
                              void* d_out, int out_size, void* d_ws, size_t ws_size,
                              hipStream_t stream)
{
    const float* x   = (const float*)d_in[0];
    const float* w1  = (const float*)d_in[1];
    const float* b1  = (const float*)d_in[2];
    const float* w2  = (const float*)d_in[3];
    const float* b2  = (const float*)d_in[4];
    const float* lnw = (const float*)d_in[5];
    const float* lnb = (const float*)d_in[6];
    float* out = (float*)d_out;

    // xt2 (chunk-major features) lives in d_out: k1 writes, k2 consumes,
    // k3 then overwrites d_out with the final output (stream-ordered).
    float* xt2 = out;

    // workspace: enh + invn + muv + rsd + w1T + w2T = 949,248 floats = 3.80 MB
    float* ws   = (float*)d_ws;
    float* enh  = ws;                        // NPIX*96
    float* invn = enh + NPIX * CH;           // NPIX
    float* muv  = invn + NPIX;               // NPIX
    float* rsd  = muv + NPIX;                // NPIX
    float* w1T  = rsd + NPIX;                // 96*192 = 18432
    float* w2T  = w1T + 192 * 96;            // 192*96 = 18432

    hipLaunchKernelGGL(k0_wt, dim3(36), dim3(256), 0, stream,
                       w1, w2, w1T, w2T);
    hipLaunchKernelGGL(k1_prep, dim3(288), dim3(256), 0, stream,
                       x, xt2, invn, muv, rsd);
    hipLaunchKernelGGL(k2_knn, dim3(NPIX / 4), dim3(256), 0, stream,
                       xt2, invn, muv, rsd, lnw, lnb, enh);
    hipLaunchKernelGGL(k3_ffn, dim3(2304), dim3(192), 0, stream,
                       enh, w1T, b1, w2T, b2, out);
}

// Round 19
// 75.609 us; speedup vs baseline: 2.4280x; 1.0098x over previous
//
#include <hip/hip_runtime.h>
#include <math.h>

#define BATCH 4
#define CH    96
#define HH    48
#define WW    48
#define HWPIX (HH*WW)         // 2304
#define NPIX  (BATCH*HWPIX)   // 9216
#define WIN   13
#define WIN2  169
#define HALF  6
#define TOPK  8
#define NEGV  (-1000000000.0f)

// ---------------------------------------------------------------------------
// K0: transpose weights once: w1 [192][96] -> w1T [96][192],
//     w2 [96][192] -> w2T [192][96]. 36 blocks x 256 thr. (passing)
// ---------------------------------------------------------------------------
__global__ __launch_bounds__(256) void k0_wt(
    const float* __restrict__ w1, const float* __restrict__ w2,
    float* __restrict__ w1T, float* __restrict__ w2T)
{
    __shared__ float tile[32][33];
    int bid = blockIdx.x;          // 0..17: w1 (6x3 tiles), 18..35: w2 (3x6)
    const float* src; float* dst; int R, C, tr, tc;
    if (bid < 18) { src = w1; dst = w1T; R = 192; C = 96;  tr = bid / 3; tc = bid % 3; }
    else { int b2 = bid - 18; src = w2; dst = w2T; R = 96; C = 192; tr = b2 / 6; tc = b2 % 6; }
    int r0 = tr * 32, c0 = tc * 32;
    int tx = threadIdx.x & 31, ty = threadIdx.x >> 5;   // ty 0..7

    #pragma unroll
    for (int i = 0; i < 4; ++i) {
        int r = ty + i * 8;
        tile[r][tx] = src[(r0 + r) * C + c0 + tx];
    }
    __syncthreads();
    #pragma unroll
    for (int i = 0; i < 4; ++i) {
        int r = ty + i * 8;
        dst[(c0 + r) * R + r0 + tx] = tile[tx][r];   // dst[c][r] = src[r][c]
    }
}

// ---------------------------------------------------------------------------
// K1: x (B,C,H,W) -> xt2 CHUNK-MAJOR [(c/4)][pixel] float4 cells (in d_out),
//     + per-pixel invn / mu / rstd. 576 blocks x 256 thr, 16 px/block
//     (doubled parallelism vs round-18's 288 blocks).
// ---------------------------------------------------------------------------
__global__ __launch_bounds__(256) void k1_prep(
    const float* __restrict__ x, float* __restrict__ xt2,
    float* __restrict__ invn, float* __restrict__ muv, float* __restrict__ rsd)
{
    __shared__ float lds[96][17];
    int bid = blockIdx.x;          // 576 = 4 batches * 144 tiles
    int b   = bid / 144;
    int p0  = (bid % 144) * 16;
    int t   = threadIdx.x;

    #pragma unroll
    for (int it = 0; it < 6; ++it) {
        int e = t + it * 256;      // 1536 = 96c * 16px
        int c = e >> 4;
        int p = e & 15;
        lds[c][p] = x[(b * CH + c) * HWPIX + p0 + p];
    }
    __syncthreads();

    if (t < 16) {
        float s = 0.f, ss = 0.f;
        #pragma unroll
        for (int c = 0; c < CH; ++c) { float v = lds[c][t]; s += v; ss += v * v; }
        int gpix = b * HWPIX + p0 + t;
        invn[gpix] = 1.0f / fmaxf(sqrtf(ss), 1e-12f);
        float m = s * (1.0f / 96.0f);
        muv[gpix] = m;
        rsd[gpix] = rsqrtf(ss * (1.0f / 96.0f) - m * m + 1e-5f);
    }

    // chunk-major write: 384 float4 cells (16 px * 24 chunks)
    float4* x4 = (float4*)xt2;
    if (t < 384) {
        int p = t & 15;
        int s = t >> 4;            // chunk 0..23
        float4 v = make_float4(lds[4*s][p], lds[4*s+1][p],
                               lds[4*s+2][p], lds[4*s+3][p]);
        x4[s * NPIX + b * HWPIX + p0 + p] = v;
    } else {
        int i = t - 384;           // second half: 128 remaining? no -- 384 total
        (void)i;
    }
    // (384 cells total; threads 384..511 unused in a 256-thr block never occur)
    if (t >= 256) return;          // unreachable guard (256-thr block)
    // handle cells 256..383 with threads 0..127
    if (t < 128) {
        int i = t + 256;
        int p = i & 15;
        int s = i >> 4;
        float4 v = make_float4(lds[4*s][p], lds[4*s+1][p],
                               lds[4*s+2][p], lds[4*s+3][p]);
        x4[s * NPIX + b * HWPIX + p0 + p] = v;
    }
}

// ---------------------------------------------------------------------------
// K2: one pixel per wave, 2304 blocks x 256 thr, chunk-major reads,
//     ballot top-8, LN stats from k1. (passing, unchanged)
// ---------------------------------------------------------------------------
__global__ __launch_bounds__(256) void k2_knn(
    const float* __restrict__ xt2, const float* __restrict__ invn,
    const float* __restrict__ muv, const float* __restrict__ rsd,
    const float* __restrict__ lnw, const float* __restrict__ lnb,
    float* __restrict__ enh)
{
    __shared__ float own[4][96];
    int t    = threadIdx.x;
    int wv   = t >> 6;
    int lane = t & 63;
    int gp   = blockIdx.x * 4 + wv;
    int b    = gp / HWPIX;
    int p    = gp - b * HWPIX;
    int py   = p / WW;
    int px   = p - py * WW;
    const float4* x4 = (const float4*)xt2;

    float4 ownv = make_float4(0.f, 0.f, 0.f, 0.f);
    if (lane < 24) {
        ownv = x4[lane * NPIX + gp];
        ((float4*)(own[wv]))[lane] = ownv;
    }
    float inp = invn[gp];
    float mu  = muv[gp];
    float rs  = rsd[gp];

    float v0 = -2e9f, v1 = -2e9f, v2 = -2e9f;
    const float4* ov = (const float4*)(own[wv]);
    #pragma unroll
    for (int k = 0; k < 3; ++k) {
        int n = lane + 64 * k;
        float sim = -2e9f;
        if (n < WIN2) {
            int dy = n / WIN - HALF;
            int dx = n - (dy + HALF) * WIN - HALF;
            int ny = py + dy, nx = px + dx;
            if (ny >= 0 && ny < HH && nx >= 0 && nx < WW) {
                int q = b * HWPIX + ny * WW + nx;
                float inq = invn[q];
                const float4* rp = x4 + q;
                float ax = 0.f, ay = 0.f, az = 0.f, aw = 0.f;
                #pragma unroll
                for (int s = 0; s < 24; ++s) {
                    float4 a  = ov[s];
                    float4 bb = rp[s * NPIX];
                    ax += a.x * bb.x; ay += a.y * bb.y;
                    az += a.z * bb.z; aw += a.w * bb.w;
                }
                sim = ((ax + ay) + (az + aw)) * inp * inq;
            } else {
                sim = NEGV;
            }
        }
        if (k == 0) v0 = sim; else if (k == 1) v1 = sim; else v2 = sim;
    }

    float tv[TOPK]; int tn[TOPK];
    #pragma unroll
    for (int r = 0; r < TOPK; ++r) {
        float m = fmaxf(fmaxf(v0, v1), v2);
        #pragma unroll
        for (int off = 1; off < 64; off <<= 1)
            m = fmaxf(m, __shfl_xor(m, off));
        unsigned long long m0 = __ballot(v0 == m);
        unsigned long long m1 = __ballot(v1 == m);
        unsigned long long m2 = __ballot(v2 == m);
        int n;
        if (m0)      n = (int)__builtin_ctzll(m0);
        else if (m1) n = 64 + (int)__builtin_ctzll(m1);
        else         n = 128 + (int)__builtin_ctzll(m2);
        tv[r] = m; tn[r] = n;
        int kk = n >> 6, ll = n & 63;
        if (ll == lane) {
            if (kk == 0)      v0 = -2e9f;
            else if (kk == 1) v1 = -2e9f;
            else              v2 = -2e9f;
        }
    }

    float wts[TOPK]; int qn[TOPK];
    float wsum = 0.f;
    #pragma unroll
    for (int r = 0; r < TOPK; ++r) {
        float e = expf(tv[r] - tv[0]);
        wts[r] = e; wsum += e;
        int n  = tn[r];
        int dy = n / WIN - HALF;
        int dx = n - (dy + HALF) * WIN - HALF;
        int gy = min(max(py + dy, 0), HH - 1);
        int gx = min(max(px + dx, 0), WW - 1);
        qn[r]  = b * HWPIX + gy * WW + gx;
    }
    float winv = 1.0f / wsum;

    if (lane < 24) {
        const float4* base = x4 + lane * NPIX;
        float4 g = make_float4(0.f, 0.f, 0.f, 0.f);
        #pragma unroll
        for (int r = 0; r < TOPK; ++r) {
            float4 f = base[qn[r]];
            float w = wts[r];
            g.x += w * f.x; g.y += w * f.y;
            g.z += w * f.z; g.w += w * f.w;
        }
        float4 lw = ((const float4*)lnw)[lane];
        float4 lb = ((const float4*)lnb)[lane];
        float4 e;
        e.x = g.x * winv + (ownv.x - mu) * rs * lw.x + lb.x;
        e.y = g.y * winv + (ownv.y - mu) * rs * lw.y + lb.y;
        e.z = g.z * winv + (ownv.z - mu) * rs * lw.z + lb.z;
        e.w = g.w * winv + (ownv.w - mu) * rs * lw.w + lb.w;
        ((float4*)(enh + gp * CH))[lane] = e;
    }
}

// ---------------------------------------------------------------------------
// K3: fused FFN, weight-amortized: 8 px/block, 1152 blocks x 192 thr.
//     Phase A: thread = j (lane-consecutive weight loads, 1x per 8 px);
//              8 block-uniform pixel rows via s_load; 8 accumulators.
//     Phase B: c = t%96, half = t/96; each handles 4 pixels (4 acc);
//              hl reads are 2-way broadcast max (free).
// ---------------------------------------------------------------------------
__global__ __launch_bounds__(192) void k3_ffn(
    const float* __restrict__ enh, const float* __restrict__ w1T,
    const float* __restrict__ b1, const float* __restrict__ w2T,
    const float* __restrict__ b2, float* __restrict__ out)
{
    __shared__ float hl[8][200];   // 6.25 KB, 800 B rows
    int g  = blockIdx.x;           // 1152 = 4 batches * 288 tiles
    int b  = g / 288;
    int p0 = (g % 288) * 8;
    int t  = threadIdx.x;
    const float4* ebase = (const float4*)(enh + (b * HWPIX + p0) * CH); // rows @ r*24

    // phase A: one hidden unit j for 8 block-uniform pixels
    {
        int j = t;                 // 0..191
        float a0=0.f,a1=0.f,a2=0.f,a3=0.f,a4=0.f,a5=0.f,a6=0.f,a7=0.f;
        #pragma unroll 4
        for (int c4 = 0; c4 < 24; ++c4) {
            float wa = w1T[(4*c4 + 0) * 192 + j];   // lane-consecutive j
            float wb = w1T[(4*c4 + 1) * 192 + j];
            float wc = w1T[(4*c4 + 2) * 192 + j];
            float wd = w1T[(4*c4 + 3) * 192 + j];
            float4 v0 = ebase[0*24 + c4];           // block-uniform -> s_load
            float4 v1 = ebase[1*24 + c4];
            float4 v2 = ebase[2*24 + c4];
            float4 v3 = ebase[3*24 + c4];
            float4 v4 = ebase[4*24 + c4];
            float4 v5 = ebase[5*24 + c4];
            float4 v6 = ebase[6*24 + c4];
            float4 v7 = ebase[7*24 + c4];
            a0 += v0.x*wa + v0.y*wb + v0.z*wc + v0.w*wd;
            a1 += v1.x*wa + v1.y*wb + v1.z*wc + v1.w*wd;
            a2 += v2.x*wa + v2.y*wb + v2.z*wc + v2.w*wd;
            a3 += v3.x*wa + v3.y*wb + v3.z*wc + v3.w*wd;
            a4 += v4.x*wa + v4.y*wb + v4.z*wc + v4.w*wd;
            a5 += v5.x*wa + v5.y*wb + v5.z*wc + v5.w*wd;
            a6 += v6.x*wa + v6.y*wb + v6.z*wc + v6.w*wd;
            a7 += v7.x*wa + v7.y*wb + v7.z*wc + v7.w*wd;
        }
        float bj = b1[j];
        hl[0][j] = fmaxf(a0 + bj, 0.f);
        hl[1][j] = fmaxf(a1 + bj, 0.f);
        hl[2][j] = fmaxf(a2 + bj, 0.f);
        hl[3][j] = fmaxf(a3 + bj, 0.f);
        hl[4][j] = fmaxf(a4 + bj, 0.f);
        hl[5][j] = fmaxf(a5 + bj, 0.f);
        hl[6][j] = fmaxf(a6 + bj, 0.f);
        hl[7][j] = fmaxf(a7 + bj, 0.f);
    }
    __syncthreads();

    // phase B: c = t%96, half = t/96; 4 pixels (half*4 .. half*4+3)
    {
        int c    = (t >= 96) ? t - 96 : t;
        int half = (t >= 96) ? 1 : 0;
        int q0p  = half * 4;
        const float4* h0 = (const float4*)(&hl[q0p    ][0]);
        const float4* h1 = (const float4*)(&hl[q0p + 1][0]);
        const float4* h2 = (const float4*)(&hl[q0p + 2][0]);
        const float4* h3 = (const float4*)(&hl[q0p + 3][0]);
        float s0 = 0.f, s1 = 0.f, s2 = 0.f, s3 = 0.f;
        #pragma unroll 6
        for (int j4 = 0; j4 < 48; ++j4) {
            float wa = w2T[(4*j4 + 0) * 96 + c];    // lane-consecutive c
            float wb = w2T[(4*j4 + 1) * 96 + c];
            float wc = w2T[(4*j4 + 2) * 96 + c];
            float wd = w2T[(4*j4 + 3) * 96 + c];
            float4 u0 = h0[j4], u1 = h1[j4], u2 = h2[j4], u3 = h3[j4];
            s0 += u0.x*wa + u0.y*wb + u0.z*wc + u0.w*wd;
            s1 += u1.x*wa + u1.y*wb + u1.z*wc + u1.w*wd;
            s2 += u2.x*wa + u2.y*wb + u2.z*wc + u2.w*wd;
            s3 += u3.x*wa + u3.y*wb + u3.z*wc + u3.w*wd;
        }
        float bc = b2[c];
        int pb = p0 + q0p;
        out[(b * CH + c) * HWPIX + pb + 0] =
            enh[(b * HWPIX + pb + 0) * CH + c] + s0 + bc;
        out[(b * CH + c) * HWPIX + pb + 1] =
            enh[(b * HWPIX + pb + 1) * CH + c] + s1 + bc;
        out[(b * CH + c) * HWPIX + pb + 2] =
            enh[(b * HWPIX + pb + 2) * CH + c] + s2 + bc;
        out[(b * CH + c) * HWPIX + pb + 3] =
            enh[(b * HWPIX + pb + 3) * CH + c] + s3 + bc;
    }
}

// ---------------------------------------------------------------------------
extern "C" void kernel_launch(void* const* d_in, const int* in_sizes, int n_in,
                              void* d_out, int out_size, void* d_ws, size_t ws_size,
                              hipStream_t stream)
{
    const float* x   = (const float*)d_in[0];
    const float* w1  = (const float*)d_in[1];
    const float* b1  = (const float*)d_in[2];
    const float* w2  = (const float*)d_in[3];
    const float* b2  = (const float*)d_in[4];
    const float* lnw = (const float*)d_in[5];
    const float* lnb = (const float*)d_in[6];
    float* out = (float*)d_out;

    // xt2 (chunk-major features) lives in d_out: k1 writes, k2 consumes,
    // k3 then overwrites d_out with the final output (stream-ordered).
    float* xt2 = out;

    // workspace: enh + invn + muv + rsd + w1T + w2T = 949,248 floats = 3.80 MB
    float* ws   = (float*)d_ws;
    float* enh  = ws;                        // NPIX*96
    float* invn = enh + NPIX * CH;           // NPIX
    float* muv  = invn + NPIX;               // NPIX
    float* rsd  = muv + NPIX;                // NPIX
    float* w1T  = rsd + NPIX;                // 96*192 = 18432
    float* w2T  = w1T + 192 * 96;            // 192*96 = 18432

    hipLaunchKernelGGL(k0_wt, dim3(36), dim3(256), 0, stream,
                       w1, w2, w1T, w2T);
    hipLaunchKernelGGL(k1_prep, dim3(576), dim3(256), 0, stream,
                       x, xt2, invn, muv, rsd);
    hipLaunchKernelGGL(k2_knn, dim3(NPIX / 4), dim3(256), 0, stream,
                       xt2, invn, muv, rsd, lnw, lnb, enh);
    hipLaunchKernelGGL(k3_ffn, dim3(1152), dim3(192), 0, stream,
                       enh, w1T, b1, w2T, b2, out);
}